// Round 4
// baseline (254.092 us; speedup 1.0000x reference)
//
#include <hip/hip_runtime.h>

// Problem constants (from reference)
#define BATCH 16384
#define DI 2048      // INPUT_DELAY_SIZE * INPUT_SIZE
#define DO 64        // OUTPUT_DELAY_SIZE * OUTPUT_SIZE
#define IS 64        // INPUT_SIZE

// Native clang vector type — __builtin_nontemporal_store rejects HIP's
// float4 class wrapper but accepts ext_vector_type.
typedef float v4f __attribute__((ext_vector_type(4)));

// One WAVE (64 lanes) per batch row; block = 256 threads = 4 rows.
// Lane l owns 8 interleaved float4 chunks of itdl (k = j*256 + l*4) so every
// load/store is a fully coalesced 1 KB wave transaction.
//
// R4 = R3 retry: ALL global stores nontemporal (nt). Theory: plain stores to
// the 138 MB d_out cause write-allocate/RFO traffic (hidden ~135 MB fetch +
// dirty evictions), explaining the 82 us plateau (= harness 554 MB fill time).
__global__ __launch_bounds__(256) void arx_cell_kernel(
    const float* __restrict__ input,   // [B, 64]
    const float* __restrict__ itdl,    // [B, 2048]
    const float* __restrict__ otdl,    // [B, 64]
    const float* __restrict__ iw,      // [2048]
    const float* __restrict__ ow,      // [64]
    const float* __restrict__ bias,    // [1]
    float* __restrict__ out)           // [B] ++ [B*2048] ++ [B*64]
{
    const int t    = threadIdx.x;
    const int lane = t & 63;
    const int row  = blockIdx.x * 4 + (t >> 6);

    const float* it = itdl + (size_t)row * DI;
    float* out0 = out;                              // outputs  [B]
    float* o1   = out + BATCH + (size_t)row * DI;   // itdl_new row
    float* o2   = out + BATCH + (size_t)BATCH * DI  // otdl_new row
                      + (size_t)row * DO;

    // ---- issue all itdl loads (8 dwordx4 per lane) ----
    v4f v[8];
    #pragma unroll
    for (int j = 0; j < 8; ++j)
        v[j] = *(const v4f*)(it + j * 256 + lane * 4);

    // input tail (lanes 0..15 cover input[row][0:64])
    v4f in0 = (v4f)(0.f);
    if (lane < 16)
        in0 = *(const v4f*)(input + (size_t)row * IS + lane * 4);

    // otdl (one element per lane)
    float oval = otdl[(size_t)row * DO + lane];

    // ---- dot products (iw/ow hot in L1/L2 across all waves) ----
    float partial = 0.f;
    #pragma unroll
    for (int j = 0; j < 8; ++j) {
        v4f wv = *(const v4f*)(iw + j * 256 + lane * 4);
        partial += v[j].x * wv.x + v[j].y * wv.y
                 + v[j].z * wv.z + v[j].w * wv.w;
    }
    partial += oval * ow[lane];

    // ---- itdl_new: shift-by-64 copy, nontemporal stores ----
    #pragma unroll
    for (int j = 0; j < 8; ++j) {
        const int k = j * 256 + lane * 4;
        if (j == 0) {
            if (lane < 16) {
                __builtin_nontemporal_store(in0, (v4f*)(o1 + (DI - IS) + lane * 4));
            } else {
                __builtin_nontemporal_store(v[j], (v4f*)(o1 + k - IS));
            }
        } else {
            __builtin_nontemporal_store(v[j], (v4f*)(o1 + k - IS));
        }
    }

    // ---- otdl_new: shift-by-1 (positions 0..62) ----
    if (lane >= 1)
        __builtin_nontemporal_store(oval, o2 + lane - 1);

    // ---- wave reduction, no LDS / no barrier ----
    #pragma unroll
    for (int off = 32; off > 0; off >>= 1)
        partial += __shfl_down(partial, off, 64);

    if (lane == 0) {
        float a2 = partial + bias[0];
        __builtin_nontemporal_store(a2, out0 + row);      // outputs[row]
        __builtin_nontemporal_store(a2, o2 + (DO - 1));   // otdl_new tail
    }
}

extern "C" void kernel_launch(void* const* d_in, const int* in_sizes, int n_in,
                              void* d_out, int out_size, void* d_ws, size_t ws_size,
                              hipStream_t stream) {
    const float* input = (const float*)d_in[0];
    const float* itdl  = (const float*)d_in[1];
    const float* otdl  = (const float*)d_in[2];
    const float* iw    = (const float*)d_in[3];
    const float* ow    = (const float*)d_in[4];
    const float* bias  = (const float*)d_in[5];
    float* out = (float*)d_out;

    arx_cell_kernel<<<BATCH / 4, 256, 0, stream>>>(input, itdl, otdl, iw, ow, bias, out);
}